// Round 12
// baseline (99.635 us; speedup 1.0000x reference)
//
#include <hip/hip_runtime.h>
#include <math.h>

#define N_PTS 4096
#define NSEG  16
#define SEG   256            // N_PTS / NSEG
#define NFREQ 15             // harmonics 1..15
#define FDIM  32             // 1 DC + 2*15 cos/sin + 1 zero pad
#define GSZ   (FDIM * FDIM)  // 1024
#define GP_JITTER 3e-7

// ---------------------------------------------------------------------------
// Fused kernel, spill-free by construction (round-9 lesson: no per-lane
// matrix arrays -> small VGPR frame; round-8 lesson: runtime loops, small
// code). Round-12: NSEG 64->16 cuts the per-address fp64 atomic-RMW chains
// 4x (the last measurable controllable cost) and shrinks the election drain.
//
// Phase 1 (16 blocks): 256-point slice of the Fourier feature map Phi
//   (N x 32, fp64 recurrence -> fp32 LDS), accumulate G += Phi^T Phi,
//   b += Phi^T y, yy += ||y||^2 via device-scope fp64 atomics into
//   pre-zeroed ws (G = exact Gram of STORED fp32 Phi -> PSD, round-3 lesson).
// Phase 2 (last block, threadfence+counter election): coherent atomic-RMW
//   re-read of G/b/yy into 4 fixed-coordinate registers/thread.
// Phase 3a: distributed 32x32 fp64 Cholesky, 2 barriers/column, pipelined
//   raw-diagonal publish + redundant rsqrt (round-11 form).
// Phase 3b: wave-0 shuffle forward solve (4 RHS), logdet, lml.
//
// Model: K(s,t) ~= sum_{m=0..15} c_m cos(m h (s-t)), trapezoid Bochner,
// period P = (t_max-t_min) + 6.5*ell: alias exp(-21.1), truncation
// exp(-18.6) -> lml error ~1e3 worst-case vs threshold 1.6e4 (measured: 0).
// ---------------------------------------------------------------------------
__global__ __launch_bounds__(256) void fused_kernel(
    const float* __restrict__ t, const float* __restrict__ traj,
    const float* __restrict__ thf, const float* __restrict__ thl,
    const float* __restrict__ thn, const int* __restrict__ nin,
    double* __restrict__ G, double* __restrict__ b, double* __restrict__ yy,
    unsigned int* __restrict__ cnt, float* __restrict__ out)
{
    __shared__ float  sPhi[FDIM][SEG + 4];   // 32 x 260 fp32 = 33.3 KB
    __shared__ float  sy[4][SEG];            // 4 KB
    __shared__ double sw[NFREQ + 1];
    __shared__ double sL[FDIM][FDIM + 1];    // 8.4 KB (phase 3)
    __shared__ double sdiag[FDIM];           // raw updated diagonal pipeline
    __shared__ double sdinv[FDIM];           // 1/L[j][j] for the solve
    __shared__ double colbuf[2][FDIM];       // parity-double-buffered column
    __shared__ double sb[FDIM * 4];
    __shared__ double syy[4];
    __shared__ int    sLast;

    const int seg = blockIdx.x, tid = threadIdx.x;
    const int ibase = seg * SEG;

    const double tf  = (double)thf[0];
    const double ell = fabs((double)thl[0]);
    const double tn  = (double)thn[0];
    const double noise = GP_JITTER + tn * tn;
    const double t0g = (double)t[0], tNg = (double)t[N_PTS - 1];
    const double h   = 6.283185307179586 / ((tNg - t0g) + 6.5 * ell);
    const double pc  = ell * 0.3989422804014327;   // ell / sqrt(2*pi)

    // ---- phase 1: per-segment feature build + atomic accumulation ----
    if (tid <= NFREQ) {
        const double om = h * (double)tid;
        const double w  = (tid == 0) ? tf * h * pc
                        : 2.0 * tf * h * pc * exp(-0.5 * ell * ell * om * om);
        sw[tid] = sqrt(w);
    }
    for (int l = tid; l < 4 * SEG; l += 256) {
        const int d = l >> 8, ii = l & (SEG - 1);
        sy[d][ii] = traj[d * N_PTS + ibase + ii];
    }
    __syncthreads();

    {   // one thread per point (256 = SEG exactly)
        const double tt = (double)t[ibase + tid];
        double s1, c1;
        sincos(h * tt, &s1, &c1);
        sPhi[0][tid] = (float)sw[0];           // DC
        double cm = c1, sm = s1;
        sPhi[1][tid] = (float)(sw[1] * cm);
        sPhi[2][tid] = (float)(sw[1] * sm);
        #pragma unroll
        for (int m = 2; m <= NFREQ; ++m) {     // angle-addition recurrence
            const double cn = cm * c1 - sm * s1;
            const double sn = sm * c1 + cm * s1;
            cm = cn; sm = sn;
            sPhi[2 * m - 1][tid] = (float)(sw[m] * cm);
            sPhi[2 * m][tid]     = (float)(sw[m] * sm);
        }
        sPhi[FDIM - 1][tid] = 0.0f;            // zero pad column (exact)
    }
    __syncthreads();

    // G tile: 16x16 threads, 2x2 register tile covers 32x32
    {
        const int ta = tid >> 4, tb = tid & 15;
        const int a0 = 2 * ta, b0 = 2 * tb;
        double a00 = 0.0, a01 = 0.0, a10 = 0.0, a11 = 0.0;
        for (int q = 0; q < SEG; q += 4) {
            const float4 v0 = *(const float4*)&sPhi[a0][q];
            const float4 v1 = *(const float4*)&sPhi[a0 + 1][q];
            const float4 u0 = *(const float4*)&sPhi[b0][q];
            const float4 u1 = *(const float4*)&sPhi[b0 + 1][q];
            a00 += (double)v0.x * u0.x + (double)v0.y * u0.y
                 + (double)v0.z * u0.z + (double)v0.w * u0.w;
            a01 += (double)v0.x * u1.x + (double)v0.y * u1.y
                 + (double)v0.z * u1.z + (double)v0.w * u1.w;
            a10 += (double)v1.x * u0.x + (double)v1.y * u0.y
                 + (double)v1.z * u0.z + (double)v1.w * u0.w;
            a11 += (double)v1.x * u1.x + (double)v1.y * u1.y
                 + (double)v1.z * u1.z + (double)v1.w * u1.w;
        }
        atomicAdd(&G[a0 * FDIM + b0],           a00);
        atomicAdd(&G[a0 * FDIM + b0 + 1],       a01);
        atomicAdd(&G[(a0 + 1) * FDIM + b0],     a10);
        atomicAdd(&G[(a0 + 1) * FDIM + b0 + 1], a11);
    }

    if (tid < FDIM * 4) {
        const int f = tid >> 2, d = tid & 3;
        double s = 0.0;
        for (int q = 0; q < SEG; q += 4) {
            const float4 p  = *(const float4*)&sPhi[f][q];
            const float4 yv = *(const float4*)&sy[d][q];
            s += (double)p.x * (double)yv.x + (double)p.y * (double)yv.y
               + (double)p.z * (double)yv.z + (double)p.w * (double)yv.w;
        }
        atomicAdd(&b[tid], s);
    } else if (tid < FDIM * 4 + 4) {
        const int d = tid - FDIM * 4;
        double s = 0.0;
        for (int q = 0; q < SEG; q += 4) {
            const float4 yv = *(const float4*)&sy[d][q];
            s += (double)yv.x * (double)yv.x + (double)yv.y * (double)yv.y
               + (double)yv.z * (double)yv.z + (double)yv.w * (double)yv.w;
        }
        atomicAdd(&yy[d], s);
    }

    // ---- last-block election (release: fence before counter add) ----
    __threadfence();
    __syncthreads();
    if (tid == 0) sLast = (atomicAdd(cnt, 1u) == NSEG - 1);
    __syncthreads();
    if (!sLast) return;
    __threadfence();

    // ---- phase 2: coherent re-read into 4 fixed register elements ----
    int ie0, ke0, ie1, ke1, ie2, ke2, ie3, ke3;
    double m0, m1, m2, m3;
    {
        const int e0 = tid, e1 = 256 + tid, e2 = 512 + tid, e3 = 768 + tid;
        ie0 = e0 >> 5; ke0 = e0 & 31;
        ie1 = e1 >> 5; ke1 = e1 & 31;
        ie2 = e2 >> 5; ke2 = e2 & 31;
        ie3 = e3 >> 5; ke3 = e3 & 31;
        m0 = atomicAdd(&G[e0], 0.0) + ((ie0 == ke0) ? noise : 0.0);
        m1 = atomicAdd(&G[e1], 0.0) + ((ie1 == ke1) ? noise : 0.0);
        m2 = atomicAdd(&G[e2], 0.0) + ((ie2 == ke2) ? noise : 0.0);
        m3 = atomicAdd(&G[e3], 0.0) + ((ie3 == ke3) ? noise : 0.0);
    }
    if (tid == 0) sdiag[0] = m0;              // element (0,0) lives on tid 0
    if (tid < FDIM * 4) sb[tid] = atomicAdd(&b[tid], 0.0);
    else if (tid < FDIM * 4 + 4) syy[tid - FDIM * 4] = atomicAdd(&yy[tid - FDIM * 4], 0.0);
    __syncthreads();

    // ---- phase 3a: distributed Cholesky, redundant rsqrt, 2 barriers/col ----
    const double dfloor = 1e-6 * noise;   // guard (Schur comps >= noise)
    for (int j = 0; j < FDIM; ++j) {
        const int par = j & 1;
        const double dj  = fmax(sdiag[j], dfloor);   // broadcast LDS read
        const double inv = rsqrt(dj);
        const double s   = dj * inv;
        if (ke0 == j && ie0 > j) { m0 *= inv; colbuf[par][ie0] = m0; sL[ie0][j] = m0; }
        if (ke1 == j && ie1 > j) { m1 *= inv; colbuf[par][ie1] = m1; sL[ie1][j] = m1; }
        if (ke2 == j && ie2 > j) { m2 *= inv; colbuf[par][ie2] = m2; sL[ie2][j] = m2; }
        if (ke3 == j && ie3 > j) { m3 *= inv; colbuf[par][ie3] = m3; sL[ie3][j] = m3; }
        if ((ie0 == j && ke0 == j) || (ie1 == j && ke1 == j) ||
            (ie2 == j && ke2 == j) || (ie3 == j && ke3 == j)) {
            sL[j][j] = s; sdinv[j] = inv;     // diag owner, off the chain
        }
        __syncthreads();
        if (ie0 > j && ke0 > j) { m0 -= colbuf[par][ie0] * colbuf[par][ke0];
                                  if (ie0 == j + 1 && ke0 == j + 1) sdiag[j + 1] = m0; }
        if (ie1 > j && ke1 > j) { m1 -= colbuf[par][ie1] * colbuf[par][ke1];
                                  if (ie1 == j + 1 && ke1 == j + 1) sdiag[j + 1] = m1; }
        if (ie2 > j && ke2 > j) { m2 -= colbuf[par][ie2] * colbuf[par][ke2];
                                  if (ie2 == j + 1 && ke2 == j + 1) sdiag[j + 1] = m2; }
        if (ie3 > j && ke3 > j) { m3 -= colbuf[par][ie3] * colbuf[par][ke3];
                                  if (ie3 == j + 1 && ke3 == j + 1) sdiag[j + 1] = m3; }
        __syncthreads();
    }

    // ---- phase 3b: wave-0 shuffle solve (4 RHS) + logdet + assembly ----
    if (tid < 64) {
        const int i = tid;
        const bool act = (i < FDIM);
        const double myinv = act ? sdinv[i] : 0.0;
        double r0 = act ? sb[i * 4 + 0] : 0.0;
        double r1 = act ? sb[i * 4 + 1] : 0.0;
        double r2 = act ? sb[i * 4 + 2] : 0.0;
        double r3 = act ? sb[i * 4 + 3] : 0.0;
        double q = 0.0;
        for (int j = 0; j < FDIM; ++j) {
            const double invj = __shfl(myinv, j);
            const double u0 = __shfl(r0, j) * invj;
            const double u1 = __shfl(r1, j) * invj;
            const double u2 = __shfl(r2, j) * invj;
            const double u3 = __shfl(r3, j) * invj;
            if (i == j) q = u0 * u0 + u1 * u1 + u2 * u2 + u3 * u3;
            const double lij = (act && i > j) ? sL[i][j] : 0.0;
            r0 -= lij * u0; r1 -= lij * u1; r2 -= lij * u2; r3 -= lij * u3;
        }
        double ldv = act ? 2.0 * log(sL[i][i]) : 0.0;   // off the serial chain
        #pragma unroll
        for (int s = 32; s > 0; s >>= 1) {
            q   += __shfl_down(q, s);
            ldv += __shfl_down(ldv, s);
        }
        if (tid == 0) {
            const double sumyy = syy[0] + syy[1] + syy[2] + syy[3];
            const double quad = (sumyy - q) / noise;
            const double logdetA = (double)(N_PTS - FDIM) * log(noise) + ldv;
            const double lml = 0.5 * quad + 0.5 * logdetA
                             + 0.5 * (double)nin[0] * 1.8378770664093453;
            out[0] = (float)lml;
        }
    }
}

extern "C" void kernel_launch(void* const* d_in, const int* in_sizes, int n_in,
                              void* d_out, int out_size, void* d_ws, size_t ws_size,
                              hipStream_t stream) {
    const float* traj = (const float*)d_in[0];   // [4, 4096]
    const float* t    = (const float*)d_in[1];   // [4096] sorted
    const float* thf  = (const float*)d_in[2];
    const float* thl  = (const float*)d_in[3];
    const float* thn  = (const float*)d_in[4];
    const int*   nn   = (const int*)d_in[5];
    float* out = (float*)d_out;

    // ws: G (1024 d) | b (128 d) | yy (4 d) | cnt  = 9256 B
    double* G  = (double*)d_ws;
    double* b  = G + GSZ;
    double* yy = b + FDIM * 4;
    unsigned int* cnt = (unsigned int*)(yy + 4);

    hipMemsetAsync(d_ws, 0, (size_t)(GSZ + FDIM * 4 + 4 + 1) * sizeof(double), stream);
    fused_kernel<<<NSEG, 256, 0, stream>>>(t, traj, thf, thl, thn, nn,
                                           G, b, yy, cnt, out);
}

// Round 13
// 96.270 us; speedup vs baseline: 1.0350x; 1.0350x over previous
//
#include <hip/hip_runtime.h>
#include <math.h>

#define N_PTS 4096
#define NSEG  64
#define SEG   64             // N_PTS / NSEG
#define NFREQ 15             // harmonics 1..15
#define FDIM  32             // 1 DC + 2*15 cos/sin + 1 zero pad
#define GSZ   (FDIM * FDIM)  // 1024
#define GP_JITTER 3e-7

// ---------------------------------------------------------------------------
// Fused kernel, spill-free by construction (round-9 lesson: no per-lane
// matrix arrays -> small VGPR frame for ALL phases; round-8 lesson: runtime
// loops, small code). Round-13: revert to the round-11 best (NSEG=64,
// 97.13 us) -- rounds 11/12 proved phase-3 path and atomic depth are both
// below the harness poison-fill floor (top-5 = fillBufferAligned, 262 MB
// at 85% HBM peak), so the best-known configuration is frozen.
//
// Phase 1 (64 blocks): 64-point slice of the Fourier feature map Phi
//   (N x 32, fp64 recurrence -> fp32 LDS), accumulate G += Phi^T Phi,
//   b += Phi^T y, yy += ||y||^2 via device-scope fp64 atomics into
//   pre-zeroed ws (G = exact Gram of STORED fp32 Phi -> PSD, round-3 lesson).
// Phase 2 (last block, threadfence+counter election): coherent atomic-RMW
//   re-read of G/b/yy into 4 fixed-coordinate registers/thread.
// Phase 3a: distributed 32x32 fp64 Cholesky, 2 barriers/column, pipelined
//   raw-diagonal publish + redundant rsqrt (round-11 form).
// Phase 3b: wave-0 shuffle forward solve (4 RHS), logdet, lml.
//
// Model: K(s,t) ~= sum_{m=0..15} c_m cos(m h (s-t)), trapezoid Bochner,
// period P = (t_max-t_min) + 6.5*ell: alias exp(-21.1), truncation
// exp(-18.6) -> lml error ~1e3 worst-case vs threshold 1.6e4 (measured: 0).
// ---------------------------------------------------------------------------
__global__ __launch_bounds__(256) void fused_kernel(
    const float* __restrict__ t, const float* __restrict__ traj,
    const float* __restrict__ thf, const float* __restrict__ thl,
    const float* __restrict__ thn, const int* __restrict__ nin,
    double* __restrict__ G, double* __restrict__ b, double* __restrict__ yy,
    unsigned int* __restrict__ cnt, float* __restrict__ out)
{
    __shared__ float  sPhi[FDIM][SEG + 4];   // 32 x 68 fp32 = 8.7 KB
    __shared__ float  sy[4][SEG];            // 1 KB
    __shared__ double sw[NFREQ + 1];
    __shared__ double sL[FDIM][FDIM + 1];    // 8.4 KB (phase 3)
    __shared__ double sdiag[FDIM];           // raw updated diagonal pipeline
    __shared__ double sdinv[FDIM];           // 1/L[j][j] for the solve
    __shared__ double colbuf[2][FDIM];       // parity-double-buffered column
    __shared__ double sb[FDIM * 4];
    __shared__ double syy[4];
    __shared__ int    sLast;

    const int seg = blockIdx.x, tid = threadIdx.x;
    const int ibase = seg * SEG;

    const double tf  = (double)thf[0];
    const double ell = fabs((double)thl[0]);
    const double tn  = (double)thn[0];
    const double noise = GP_JITTER + tn * tn;
    const double t0g = (double)t[0], tNg = (double)t[N_PTS - 1];
    const double h   = 6.283185307179586 / ((tNg - t0g) + 6.5 * ell);
    const double pc  = ell * 0.3989422804014327;   // ell / sqrt(2*pi)

    // ---- phase 1: per-segment feature build + atomic accumulation ----
    if (tid <= NFREQ) {
        const double om = h * (double)tid;
        const double w  = (tid == 0) ? tf * h * pc
                        : 2.0 * tf * h * pc * exp(-0.5 * ell * ell * om * om);
        sw[tid] = sqrt(w);
    }
    {
        const int d = tid >> 6, ii = tid & (SEG - 1);   // 256 = 4*64 exactly
        sy[d][ii] = traj[d * N_PTS + ibase + ii];
    }
    __syncthreads();

    if (tid < SEG) {
        const double tt = (double)t[ibase + tid];
        double s1, c1;
        sincos(h * tt, &s1, &c1);
        sPhi[0][tid] = (float)sw[0];           // DC
        double cm = c1, sm = s1;
        sPhi[1][tid] = (float)(sw[1] * cm);
        sPhi[2][tid] = (float)(sw[1] * sm);
        #pragma unroll
        for (int m = 2; m <= NFREQ; ++m) {     // angle-addition recurrence
            const double cn = cm * c1 - sm * s1;
            const double sn = sm * c1 + cm * s1;
            cm = cn; sm = sn;
            sPhi[2 * m - 1][tid] = (float)(sw[m] * cm);
            sPhi[2 * m][tid]     = (float)(sw[m] * sm);
        }
        sPhi[FDIM - 1][tid] = 0.0f;            // zero pad column (exact)
    }
    __syncthreads();

    // G tile: 16x16 threads, 2x2 register tile covers 32x32
    {
        const int ta = tid >> 4, tb = tid & 15;
        const int a0 = 2 * ta, b0 = 2 * tb;
        double a00 = 0.0, a01 = 0.0, a10 = 0.0, a11 = 0.0;
        for (int q = 0; q < SEG; q += 4) {
            const float4 v0 = *(const float4*)&sPhi[a0][q];
            const float4 v1 = *(const float4*)&sPhi[a0 + 1][q];
            const float4 u0 = *(const float4*)&sPhi[b0][q];
            const float4 u1 = *(const float4*)&sPhi[b0 + 1][q];
            a00 += (double)v0.x * u0.x + (double)v0.y * u0.y
                 + (double)v0.z * u0.z + (double)v0.w * u0.w;
            a01 += (double)v0.x * u1.x + (double)v0.y * u1.y
                 + (double)v0.z * u1.z + (double)v0.w * u1.w;
            a10 += (double)v1.x * u0.x + (double)v1.y * u0.y
                 + (double)v1.z * u0.z + (double)v1.w * u0.w;
            a11 += (double)v1.x * u1.x + (double)v1.y * u1.y
                 + (double)v1.z * u1.z + (double)v1.w * u1.w;
        }
        atomicAdd(&G[a0 * FDIM + b0],           a00);
        atomicAdd(&G[a0 * FDIM + b0 + 1],       a01);
        atomicAdd(&G[(a0 + 1) * FDIM + b0],     a10);
        atomicAdd(&G[(a0 + 1) * FDIM + b0 + 1], a11);
    }

    if (tid < FDIM * 4) {
        const int f = tid >> 2, d = tid & 3;
        double s = 0.0;
        for (int q = 0; q < SEG; q += 4) {
            const float4 p  = *(const float4*)&sPhi[f][q];
            const float4 yv = *(const float4*)&sy[d][q];
            s += (double)p.x * (double)yv.x + (double)p.y * (double)yv.y
               + (double)p.z * (double)yv.z + (double)p.w * (double)yv.w;
        }
        atomicAdd(&b[tid], s);
    } else if (tid < FDIM * 4 + 4) {
        const int d = tid - FDIM * 4;
        double s = 0.0;
        for (int q = 0; q < SEG; q += 4) {
            const float4 yv = *(const float4*)&sy[d][q];
            s += (double)yv.x * (double)yv.x + (double)yv.y * (double)yv.y
               + (double)yv.z * (double)yv.z + (double)yv.w * (double)yv.w;
        }
        atomicAdd(&yy[d], s);
    }

    // ---- last-block election (release: fence before counter add) ----
    __threadfence();
    __syncthreads();
    if (tid == 0) sLast = (atomicAdd(cnt, 1u) == NSEG - 1);
    __syncthreads();
    if (!sLast) return;
    __threadfence();

    // ---- phase 2: coherent re-read into 4 fixed register elements ----
    int ie0, ke0, ie1, ke1, ie2, ke2, ie3, ke3;
    double m0, m1, m2, m3;
    {
        const int e0 = tid, e1 = 256 + tid, e2 = 512 + tid, e3 = 768 + tid;
        ie0 = e0 >> 5; ke0 = e0 & 31;
        ie1 = e1 >> 5; ke1 = e1 & 31;
        ie2 = e2 >> 5; ke2 = e2 & 31;
        ie3 = e3 >> 5; ke3 = e3 & 31;
        m0 = atomicAdd(&G[e0], 0.0) + ((ie0 == ke0) ? noise : 0.0);
        m1 = atomicAdd(&G[e1], 0.0) + ((ie1 == ke1) ? noise : 0.0);
        m2 = atomicAdd(&G[e2], 0.0) + ((ie2 == ke2) ? noise : 0.0);
        m3 = atomicAdd(&G[e3], 0.0) + ((ie3 == ke3) ? noise : 0.0);
    }
    if (tid == 0) sdiag[0] = m0;              // element (0,0) lives on tid 0
    if (tid < FDIM * 4) sb[tid] = atomicAdd(&b[tid], 0.0);
    else if (tid < FDIM * 4 + 4) syy[tid - FDIM * 4] = atomicAdd(&yy[tid - FDIM * 4], 0.0);
    __syncthreads();

    // ---- phase 3a: distributed Cholesky, redundant rsqrt, 2 barriers/col ----
    const double dfloor = 1e-6 * noise;   // guard (Schur comps >= noise)
    for (int j = 0; j < FDIM; ++j) {
        const int par = j & 1;
        const double dj  = fmax(sdiag[j], dfloor);   // broadcast LDS read
        const double inv = rsqrt(dj);
        const double s   = dj * inv;
        if (ke0 == j && ie0 > j) { m0 *= inv; colbuf[par][ie0] = m0; sL[ie0][j] = m0; }
        if (ke1 == j && ie1 > j) { m1 *= inv; colbuf[par][ie1] = m1; sL[ie1][j] = m1; }
        if (ke2 == j && ie2 > j) { m2 *= inv; colbuf[par][ie2] = m2; sL[ie2][j] = m2; }
        if (ke3 == j && ie3 > j) { m3 *= inv; colbuf[par][ie3] = m3; sL[ie3][j] = m3; }
        if ((ie0 == j && ke0 == j) || (ie1 == j && ke1 == j) ||
            (ie2 == j && ke2 == j) || (ie3 == j && ke3 == j)) {
            sL[j][j] = s; sdinv[j] = inv;     // diag owner, off the chain
        }
        __syncthreads();
        if (ie0 > j && ke0 > j) { m0 -= colbuf[par][ie0] * colbuf[par][ke0];
                                  if (ie0 == j + 1 && ke0 == j + 1) sdiag[j + 1] = m0; }
        if (ie1 > j && ke1 > j) { m1 -= colbuf[par][ie1] * colbuf[par][ke1];
                                  if (ie1 == j + 1 && ke1 == j + 1) sdiag[j + 1] = m1; }
        if (ie2 > j && ke2 > j) { m2 -= colbuf[par][ie2] * colbuf[par][ke2];
                                  if (ie2 == j + 1 && ke2 == j + 1) sdiag[j + 1] = m2; }
        if (ie3 > j && ke3 > j) { m3 -= colbuf[par][ie3] * colbuf[par][ke3];
                                  if (ie3 == j + 1 && ke3 == j + 1) sdiag[j + 1] = m3; }
        __syncthreads();
    }

    // ---- phase 3b: wave-0 shuffle solve (4 RHS) + logdet + assembly ----
    if (tid < 64) {
        const int i = tid;
        const bool act = (i < FDIM);
        const double myinv = act ? sdinv[i] : 0.0;
        double r0 = act ? sb[i * 4 + 0] : 0.0;
        double r1 = act ? sb[i * 4 + 1] : 0.0;
        double r2 = act ? sb[i * 4 + 2] : 0.0;
        double r3 = act ? sb[i * 4 + 3] : 0.0;
        double q = 0.0;
        for (int j = 0; j < FDIM; ++j) {
            const double invj = __shfl(myinv, j);
            const double u0 = __shfl(r0, j) * invj;
            const double u1 = __shfl(r1, j) * invj;
            const double u2 = __shfl(r2, j) * invj;
            const double u3 = __shfl(r3, j) * invj;
            if (i == j) q = u0 * u0 + u1 * u1 + u2 * u2 + u3 * u3;
            const double lij = (act && i > j) ? sL[i][j] : 0.0;
            r0 -= lij * u0; r1 -= lij * u1; r2 -= lij * u2; r3 -= lij * u3;
        }
        double ldv = act ? 2.0 * log(sL[i][i]) : 0.0;   // off the serial chain
        #pragma unroll
        for (int s = 32; s > 0; s >>= 1) {
            q   += __shfl_down(q, s);
            ldv += __shfl_down(ldv, s);
        }
        if (tid == 0) {
            const double sumyy = syy[0] + syy[1] + syy[2] + syy[3];
            const double quad = (sumyy - q) / noise;
            const double logdetA = (double)(N_PTS - FDIM) * log(noise) + ldv;
            const double lml = 0.5 * quad + 0.5 * logdetA
                             + 0.5 * (double)nin[0] * 1.8378770664093453;
            out[0] = (float)lml;
        }
    }
}

extern "C" void kernel_launch(void* const* d_in, const int* in_sizes, int n_in,
                              void* d_out, int out_size, void* d_ws, size_t ws_size,
                              hipStream_t stream) {
    const float* traj = (const float*)d_in[0];   // [4, 4096]
    const float* t    = (const float*)d_in[1];   // [4096] sorted
    const float* thf  = (const float*)d_in[2];
    const float* thl  = (const float*)d_in[3];
    const float* thn  = (const float*)d_in[4];
    const int*   nn   = (const int*)d_in[5];
    float* out = (float*)d_out;

    // ws: G (1024 d) | b (128 d) | yy (4 d) | cnt  = 9256 B
    double* G  = (double*)d_ws;
    double* b  = G + GSZ;
    double* yy = b + FDIM * 4;
    unsigned int* cnt = (unsigned int*)(yy + 4);

    hipMemsetAsync(d_ws, 0, (size_t)(GSZ + FDIM * 4 + 4 + 1) * sizeof(double), stream);
    fused_kernel<<<NSEG, 256, 0, stream>>>(t, traj, thf, thl, thn, nn,
                                           G, b, yy, cnt, out);
}